// Round 3
// baseline (10908.282 us; speedup 1.0000x reference)
//
#include <hip/hip_runtime.h>
#include <math.h>

#define HW 65536
#define BB 4
#define NL 5

typedef short s8v __attribute__((ext_vector_type(8)));
typedef float f4v __attribute__((ext_vector_type(4)));
typedef unsigned short u16;

__device__ __forceinline__ float leaky_f(float x){ return x >= 0.f ? x : 0.01f * x; }

__device__ __forceinline__ u16 f2bf(float x){
    union { float f; unsigned u; } v; v.f = x;
    unsigned r = v.u + 0x7FFF + ((v.u >> 16) & 1);
    return (u16)(r >> 16);
}
__device__ __forceinline__ float bf2f(u16 h){
    union { unsigned u; float f; } v; v.u = ((unsigned)h) << 16;
    return v.f;
}

// ---------------------------------------------------------------------------
// init / gradient / packs
// ---------------------------------------------------------------------------
__global__ void k_init(const float* __restrict__ src, const float* __restrict__ z0,
                       float* __restrict__ images0, float* __restrict__ resid0,
                       float* __restrict__ def){
    int p = blockIdx.x * 256 + threadIdx.x;
    int b = p >> 16, q = p & 65535;
    images0[p] = src[p];
    resid0[p]  = z0[q];
    int x = q & 255, y = q >> 8;
    def[(size_t)(b * 2 + 0) * HW + q] = (float)x;
    def[(size_t)(b * 2 + 1) * HW + q] = (float)y;
}

__global__ void k_grad(const float* __restrict__ img, float* __restrict__ gout){
    int p = blockIdx.x * 256 + threadIdx.x;
    int b = p >> 16, q = p & 65535;
    int x = q & 255, y = q >> 8;
    const float* ib = img + (size_t)b * HW;
    int xm = max(x - 1, 0), xp = min(x + 1, 255);
    int ym = max(y - 1, 0), yp = min(y + 1, 255);
    float a00 = ib[ym * 256 + xm], a01 = ib[ym * 256 + x], a02 = ib[ym * 256 + xp];
    float a10 = ib[y  * 256 + xm],                         a12 = ib[y  * 256 + xp];
    float a20 = ib[yp * 256 + xm], a21 = ib[yp * 256 + x], a22 = ib[yp * 256 + xp];
    float gx = (a02 - a00 + 2.f * (a12 - a10) + a22 - a20) * 0.125f;
    float gy = (a20 - a00 + 2.f * (a21 - a01) + a22 - a02) * 0.125f;
    gout[(size_t)(b * 2 + 0) * HW + q] = gx;
    gout[(size_t)(b * 2 + 1) * HW + q] = gy;
}

// conv2 weights -> MFMA fragment order (lane&15 = oc-within-tile, quad*8+j = ic-in-slab)
__global__ void k_packw(const float* __restrict__ zw2, const float* __restrict__ vw2,
                        u16* __restrict__ wp){
    int idx = blockIdx.x * 256 + threadIdx.x;     // < 1,290,240
    int lane9 = idx & 511, chunk = idx >> 9;
    int nt = chunk % 7; int t = chunk / 7;
    int ks = t % 4; t >>= 2;
    int off = t % 9; t /= 9;
    int layer = t % 5, path = t / 5;
    int lane = lane9 >> 3, j = lane9 & 7;
    int ic = ks * 32 + (lane >> 4) * 8 + j;
    int oc = nt * 16 + (lane & 15);
    const float* w = path ? vw2 : zw2;
    float v = 0.f;
    if (ic < 100 && oc < 100)
        v = w[(((size_t)layer * 100 + oc) * 100 + ic) * 9 + off];
    wp[idx] = f2bf(v);
}

// conv3 weights -> contiguous [slot][chunk=off*4+ks][32] fp32 for uniform s_loads
// slots: 0..4 = z layers (n=0); 5..14 = v (layer*2+n)
__global__ void k_packw3(const float* __restrict__ zw3, const float* __restrict__ vw3,
                         float* __restrict__ wr){
    int idx = blockIdx.x * 256 + threadIdx.x;
    if (idx >= 17280) return;
    int icl = idx & 31; int row = idx >> 5;
    int chunk = row % 36; int slot = row / 36;
    int ks = chunk & 3, off = chunk >> 2;
    int ic = ks * 32 + icl;
    float v = 0.f;
    if (ic < 100){
        if (slot < 5) v = zw3[((size_t)slot * 100 + ic) * 9 + off];
        else { int t = slot - 5; int layer = t >> 1, n = t & 1;
               v = vw3[(((size_t)layer * 2 + n) * 100 + ic) * 9 + off]; }
    }
    wr[idx] = v;
}

// ---------------------------------------------------------------------------
// conv1: 3 fp32 planes -> h1 NHWC bf16[128] (leaky; oc>=100 zero)
// ---------------------------------------------------------------------------
__global__ __launch_bounds__(256)
void k_conv1(const float* __restrict__ p0, int s0, const float* __restrict__ p1, int s1,
             const float* __restrict__ p2, int s2, const float* __restrict__ w1,
             u16* __restrict__ h1, int b0){
    __shared__ float t3[300];
    __shared__ float wl[2700];
    const int tid = threadIdx.x;
    const int tX = blockIdx.x, tY = blockIdx.y, bz = blockIdx.z;
    const int b = b0 + bz;
    const int y0 = tY * 8 - 1, x0 = tX * 8 - 1;
    for (int idx = tid; idx < 300; idx += 256){
        int ch = idx / 100, p = idx - ch * 100;
        int r = p / 10, c = p - r * 10;
        int gy = y0 + r, gx = x0 + c;
        const float* pp = (ch == 0) ? p0 + (size_t)b * s0
                        : (ch == 1) ? p1 + (size_t)b * s1 : p2 + (size_t)b * s2;
        t3[idx] = ((unsigned)gy < 256u && (unsigned)gx < 256u) ? pp[gy * 256 + gx] : 0.f;
    }
    for (int idx = tid; idx < 2700; idx += 256) wl[idx] = w1[idx];
    __syncthreads();

    const int px = tid & 63, g = tid >> 6;
    const int row = px >> 3, colx = px & 7;
    float iv[27];
    #pragma unroll
    for (int c3 = 0; c3 < 3; c3++)
        #pragma unroll
        for (int dr = 0; dr < 3; dr++)
            #pragma unroll
            for (int dc = 0; dc < 3; dc++)
                iv[c3 * 9 + dr * 3 + dc] = t3[c3 * 100 + (row + dr) * 10 + colx + dc];

    const int gy = tY * 8 + row, gx = tX * 8 + colx;
    u16* dst = h1 + (((size_t)bz * HW + (size_t)(gy * 256 + gx)) << 7) + g * 32;
    #pragma unroll
    for (int s = 0; s < 4; s++){
        int ov[4];
        #pragma unroll
        for (int hp = 0; hp < 4; hp++){
            u16 lo = 0, hi = 0;
            #pragma unroll
            for (int e = 0; e < 2; e++){
                int oc = g * 32 + s * 8 + hp * 2 + e;
                u16 hv = 0;
                if (oc < 100){
                    const float* wk = &wl[oc * 27];
                    float a = 0.f;
                    #pragma unroll
                    for (int q = 0; q < 27; q++) a = fmaf(wk[q], iv[q], a);
                    hv = f2bf(leaky_f(a));
                }
                if (e) hi = hv; else lo = hv;
            }
            ov[hp] = (int)lo | ((int)hi << 16);
        }
        *(int4*)(dst + s * 8) = make_int4(ov[0], ov[1], ov[2], ov[3]);
    }
}

// ---------------------------------------------------------------------------
// swizzled halo staging: 34x10 px tile, 64B (32-short) pitch, LDS slot sl holds
// global ic-chunk (sl ^ ((px>>1)&3)). Readers of logical chunk q use slot
// q ^ ((px>>1)&3) -> bank-conflict-free on b128 reads.
// ---------------------------------------------------------------------------
__device__ __forceinline__ void slab_addr(int tid, int y0, int x0, size_t hbase,
                                          int* goff, int* loff){
    #pragma unroll
    for (int s = 0; s < 6; s++){
        int idx = tid + s * 256;
        goff[s] = -1; loff[s] = 0;
        if (idx < 1360){
            int px = idx >> 2, sl = idx & 3;
            int hr = px / 34, hc = px - hr * 34;
            int gy = y0 + hr, gx = x0 + hc;
            int ch = sl ^ ((px >> 1) & 3);
            loff[s] = px * 32 + sl * 8;
            if ((unsigned)gy < 256u && (unsigned)gx < 256u)
                goff[s] = (int)(((hbase + (size_t)(gy * 256 + gx)) << 7) + ch * 8);
        } else loff[s] = -1;
    }
}
__device__ __forceinline__ void slab_load(const u16* __restrict__ h, const int* goff,
                                          int ks, int4* sreg){
    #pragma unroll
    for (int s = 0; s < 6; s++){
        int4 v = make_int4(0, 0, 0, 0);
        if (goff[s] >= 0) v = *(const int4*)(h + goff[s] + ks * 32);
        sreg[s] = v;
    }
}
__device__ __forceinline__ void slab_store(short* lds, const int* loff, const int4* sreg){
    #pragma unroll
    for (int s = 0; s < 6; s++)
        if (loff[s] >= 0) *(int4*)&lds[loff[s]] = sreg[s];
}

// ---------------------------------------------------------------------------
// conv2: 100->100 3x3 implicit GEMM. A=weights (oc), B=activations (px).
// block 256 = 4 waves, out tile 32x8. Double-buffered swizzled staging.
// D: col=lane&15=px, row=quad*4+reg=oc -> 8B vectorized bf16 stores.
// ---------------------------------------------------------------------------
__global__ __launch_bounds__(256, 2)
void k_conv2(const u16* __restrict__ h1, const u16* __restrict__ wp, u16* __restrict__ h2){
    __shared__ __align__(16) short lds[2][10880];
    const int tid = threadIdx.x;
    const int lane = tid & 63;
    const int wv = tid >> 6;
    const int quad = lane >> 4, m = lane & 15;
    const int tX = blockIdx.x, tY = blockIdx.y, bz = blockIdx.z;
    const int y0 = tY * 8 - 1, x0 = tX * 32 - 1;
    const size_t hbase = (size_t)bz << 16;

    f4v acc[4][7];
    #pragma unroll
    for (int t = 0; t < 4; t++)
        #pragma unroll
        for (int n = 0; n < 7; n++){
            acc[t][n][0] = 0.f; acc[t][n][1] = 0.f; acc[t][n][2] = 0.f; acc[t][n][3] = 0.f;
        }

    int goff[6], loff[6];
    slab_addr(tid, y0, x0, hbase, goff, loff);
    int4 sreg[6];
    slab_load(h1, goff, 0, sreg);
    slab_store(lds[0], loff, sreg);
    __syncthreads();

    for (int ks = 0; ks < 4; ks++){
        if (ks < 3) slab_load(h1, goff, ks + 1, sreg);
        const short* L = lds[ks & 1];
        #pragma unroll
        for (int dr = 0; dr < 3; dr++)
        #pragma unroll
        for (int dc = 0; dc < 3; dc++){
            const int off = dr * 3 + dc;
            s8v bf[4];
            #pragma unroll
            for (int t = 0; t < 4; t++){
                int hpx = (2 * wv + (t >> 1) + dr) * 34 + (t & 1) * 16 + dc + m;
                bf[t] = *(const s8v*)&L[hpx * 32 + ((quad ^ ((hpx >> 1) & 3)) << 3)];
            }
            const u16* wb = wp + (size_t)((off * 4 + ks) * 7) * 512 + lane * 8;
            #pragma unroll
            for (int nt = 0; nt < 7; nt++){
                s8v af = *(const s8v*)(wb + nt * 512);
                #pragma unroll
                for (int t = 0; t < 4; t++)
                    acc[t][nt] = __builtin_amdgcn_mfma_f32_16x16x32_bf16(af, bf[t], acc[t][nt], 0, 0, 0);
            }
        }
        if (ks < 3){
            slab_store(lds[(ks + 1) & 1], loff, sreg);
            __syncthreads();
        }
    }

    // epilogue: per (t,nt) lane holds oc = nt*16 + quad*4 + {0..3} at px(m)
    #pragma unroll
    for (int t = 0; t < 4; t++){
        int gy = tY * 8 + 2 * wv + (t >> 1);
        int gx = tX * 32 + (t & 1) * 16 + m;
        u16* base = h2 + ((hbase + (size_t)(gy * 256 + gx)) << 7);
        #pragma unroll
        for (int nt = 0; nt < 7; nt++){
            unsigned lo = (unsigned)f2bf(leaky_f(acc[t][nt][0])) |
                          ((unsigned)f2bf(leaky_f(acc[t][nt][1])) << 16);
            unsigned hi = (unsigned)f2bf(leaky_f(acc[t][nt][2])) |
                          ((unsigned)f2bf(leaky_f(acc[t][nt][3])) << 16);
            *(int2*)(base + nt * 16 + quad * 4) = make_int2((int)lo, (int)hi);
        }
    }
    // oc 112..127 never written: conv3 weights are zero there (finite garbage is safe)
}

// ---------------------------------------------------------------------------
// conv3: 100->N. Same staging; weights via uniform indices -> s_load from K$.
// 1 px/thread (32x8 tile), fp32 accumulate.
// ---------------------------------------------------------------------------
template<int N>
__global__ __launch_bounds__(256, 2)
void k_conv3(const u16* __restrict__ h2, const float* __restrict__ wb,
             const float* __restrict__ rprev, float* __restrict__ out0,
             float* __restrict__ out1, int b0){
    __shared__ __align__(16) short lds[2][10880];
    const int tid = threadIdx.x;
    const int tX = blockIdx.x, tY = blockIdx.y, bz = blockIdx.z;
    const int y0 = tY * 8 - 1, x0 = tX * 32 - 1;
    const size_t hbase = (size_t)bz << 16;
    const int row = tid >> 5, col = tid & 31;

    float acc[N];
    #pragma unroll
    for (int n = 0; n < N; n++) acc[n] = 0.f;

    int goff[6], loff[6];
    slab_addr(tid, y0, x0, hbase, goff, loff);
    int4 sreg[6];
    slab_load(h2, goff, 0, sreg);
    slab_store(lds[0], loff, sreg);
    __syncthreads();

    for (int ks = 0; ks < 4; ks++){
        if (ks < 3) slab_load(h2, goff, ks + 1, sreg);
        const short* L = lds[ks & 1];
        #pragma unroll
        for (int dr = 0; dr < 3; dr++)
        #pragma unroll
        for (int dc = 0; dc < 3; dc++){
            const int hpx = (row + dr) * 34 + col + dc;
            const float* w0 = wb + ((dr * 3 + dc) * 4 + ks) * 32;
            #pragma unroll
            for (int q = 0; q < 4; q++){
                s8v a = *(const s8v*)&L[hpx * 32 + ((q ^ ((hpx >> 1) & 3)) << 3)];
                #pragma unroll
                for (int j = 0; j < 8; j++){
                    float av = bf2f((u16)a[j]);
                    #pragma unroll
                    for (int n = 0; n < N; n++)
                        acc[n] = fmaf(av, w0[n * 1152 + q * 8 + j], acc[n]);
                }
            }
        }
        if (ks < 3){
            slab_store(lds[(ks + 1) & 1], loff, sreg);
            __syncthreads();
        }
    }

    const int b = b0 + bz;
    const int gy = tY * 8 + row, gx = tX * 32 + col;
    const size_t p = (size_t)gy * 256 + gx;
    if (N == 1){
        float v = rprev[(size_t)b * HW + p] + acc[0] * 0.2f;
        out0[(size_t)b * HW + p] = v;
        out1[(size_t)b * HW + p] = v;
    } else {
        out0[((size_t)(b * 2) + 0) * HW + p] = acc[0];
        out0[((size_t)(b * 2) + 1) * HW + p] = acc[1];
    }
}

// ---------------------------------------------------------------------------
// bilinear warp + blurs + final (unchanged)
// ---------------------------------------------------------------------------
__device__ __forceinline__ float bilin(const float* __restrict__ img, float x, float y){
    float x0 = floorf(x), y0 = floorf(y);
    float wx = x - x0, wy = y - y0;
    float r = 0.f;
    #pragma unroll
    for (int dy = 0; dy < 2; dy++){
        float yi = y0 + (float)dy;
        if (yi < 0.f || yi > 255.f) continue;
        int iy = (int)yi;
        float wyv = dy ? wy : 1.f - wy;
        #pragma unroll
        for (int dx = 0; dx < 2; dx++){
            float xi = x0 + (float)dx;
            if (xi < 0.f || xi > 255.f) continue;
            int ix = (int)xi;
            float wxv = dx ? wx : 1.f - wx;
            r += wyv * wxv * img[iy * 256 + ix];
        }
    }
    return r;
}

__global__ void k_deform(const float* __restrict__ rdin, const float* __restrict__ def,
                         float* __restrict__ rdout){
    int p = blockIdx.x * 256 + threadIdx.x;
    int j = blockIdx.y;
    int b = p >> 16, q = p & 65535;
    float x = def[(size_t)(b * 2 + 0) * HW + q];
    float y = def[(size_t)(b * 2 + 1) * HW + q];
    rdout[(size_t)j * BB * HW + p] = bilin(rdin + (size_t)j * BB * HW + (size_t)b * HW, x, y);
}

__global__ void k_blur_h(const float* __restrict__ in, float* __restrict__ outb){
    __shared__ float g[51];
    __shared__ float row[306];
    __shared__ float ginv;
    int tid = threadIdx.x;
    int rid = blockIdx.x;
    int ch = rid >> 8, y = rid & 255;
    if (tid < 51){ float d = (float)tid - 25.f; g[tid] = expf(-0.005f * d * d); }
    row[tid + 25] = in[(size_t)ch * HW + y * 256 + tid];
    if (tid < 25) row[tid] = 0.f;
    if (tid >= 231) row[tid + 50] = 0.f;
    __syncthreads();
    if (tid == 0){ float s = 0.f; for (int k = 0; k < 51; k++) s += g[k]; ginv = 1.f / s; }
    __syncthreads();
    float acc = 0.f;
    for (int k = 0; k < 51; k++) acc = fmaf(g[k], row[tid + k], acc);
    outb[(size_t)ch * HW + y * 256 + tid] = acc * ginv;
}

__global__ void k_blur_v(const float* __restrict__ in, float* __restrict__ fout,
                         float* __restrict__ def){
    __shared__ float g[51];
    __shared__ float ginv;
    __shared__ float tb[82 * 64];
    int tid = threadIdx.x;
    int tX = blockIdx.x, tY = blockIdx.y, ch = blockIdx.z;
    if (tid < 51){ float d = (float)tid - 25.f; g[tid] = expf(-0.005f * d * d); }
    for (int idx = tid; idx < 82 * 64; idx += 256){
        int r = idx >> 6, c = idx & 63;
        int gy = tY * 32 + r - 25, gx = tX * 64 + c;
        tb[idx] = (gy >= 0 && gy < 256) ? in[(size_t)ch * HW + gy * 256 + gx] : 0.f;
    }
    __syncthreads();
    if (tid == 0){ float s = 0.f; for (int k = 0; k < 51; k++) s += g[k]; ginv = 1.f / s; }
    __syncthreads();
    int c = tid & 63, r0 = (tid >> 6) * 8;
    for (int k = 0; k < 8; k++){
        int r = r0 + k;
        float acc = 0.f;
        for (int t = 0; t < 51; t++) acc = fmaf(g[t], tb[(r + t) * 64 + c], acc);
        acc *= ginv;
        int y = tY * 32 + r, x = tX * 64 + c;
        fout[(size_t)ch * HW + y * 256 + x] = acc;
        def [(size_t)ch * HW + y * 256 + x] -= acc * 0.2f;
    }
}

__global__ void k_final(const float* __restrict__ def, const float* __restrict__ src,
                        const float* __restrict__ seg, const float* __restrict__ rdbase,
                        int nrd, float* __restrict__ imgout){
    int p = blockIdx.x * 256 + threadIdx.x;
    int b = p >> 16, q = p & 65535;
    float x = def[(size_t)(b * 2 + 0) * HW + q];
    float y = def[(size_t)(b * 2 + 1) * HW + q];
    float mk = bilin(seg + (size_t)b * HW, x, y);
    float s = bilin(src + (size_t)b * HW, x, y);
    float acc = 0.f;
    for (int j = 0; j < nrd; j++) acc += rdbase[(size_t)j * BB * HW + p];
    imgout[p] = s + acc * 8e-5f * mk;
}

// ---------------------------------------------------------------------------
extern "C" void kernel_launch(void* const* d_in, const int* in_sizes, int n_in,
                              void* d_out, int out_size, void* d_ws, size_t ws_size,
                              hipStream_t stream){
    const float* source = (const float*)d_in[0];
    const float* seg    = (const float*)d_in[1];
    const float* z0     = (const float*)d_in[2];
    const float* zw1    = (const float*)d_in[3];
    const float* zw2    = (const float*)d_in[4];
    const float* zw3    = (const float*)d_in[5];
    const float* vw1    = (const float*)d_in[6];
    const float* vw2    = (const float*)d_in[7];
    const float* vw3    = (const float*)d_in[8];

    float* out = (float*)d_out;
    float* images = out;                       // (6,B,1,HW)
    float* fields = out + 1572864;             // (5,B,2,HW)
    float* resid  = out + 4194304;             // (6,B,1,HW)
    float* grads  = out + 5767168;             // (6,B,2,HW)

    float* ws = (float*)d_ws;
    float* def  = ws;                          // 524288
    float* RDa  = def  + 524288;               // 1310720
    float* RDb  = RDa  + 1310720;              // 1310720
    float* vtmp = RDb  + 1310720;              // 524288
    float* btmp = vtmp + 524288;               // 524288
    u16*   wp   = (u16*)(btmp + 524288);       // 1,290,240 u16
    float* wr3  = (float*)(wp + 1290240);      // 17,280 fp32
    u16*   h1   = (u16*)(wr3 + 17280);

    size_t need4 = 4194304ull * 4 + 1290240ull * 2 + 17280ull * 4 + 2ull * 4 * 16777216ull;
    const int HB = (ws_size >= need4) ? 4 : 1;
    u16* h2 = h1 + (size_t)HB * 8388608;       // HB*HW*128

    k_packw <<<5040, 256, 0, stream>>>(zw2, vw2, wp);
    k_packw3<<<68, 256, 0, stream>>>(zw3, vw3, wr3);
    k_init  <<<1024, 256, 0, stream>>>(source, z0, images, resid, def);
    k_grad  <<<1024, 256, 0, stream>>>(source, grads);

    float* RDcur = RDa;
    float* RDnxt = RDb;

    for (int i = 0; i < NL; i++){
        float* res_i  = resid  + (size_t)i * BB * HW;
        float* res_ip = resid  + (size_t)(i + 1) * BB * HW;
        float* img_i  = images + (size_t)i * BB * HW;
        float* img_ip = images + (size_t)(i + 1) * BB * HW;

        // ---- z path ----
        for (int b0 = 0; b0 < BB; b0 += HB){
            k_conv1<<<dim3(32, 32, HB), 256, 0, stream>>>(
                res_i, HW, img_i, HW, images, HW, zw1 + (size_t)i * 2700, h1, b0);
            k_conv2<<<dim3(8, 32, HB), 256, 0, stream>>>(
                h1, wp + (size_t)i * 129024, h2);
            k_conv3<1><<<dim3(8, 32, HB), 256, 0, stream>>>(
                h2, wr3 + (size_t)i * 1152, res_i, res_ip,
                RDnxt + (size_t)i * BB * HW, b0);
        }

        // ---- deform previously-deformed residuals (pre-update def) ----
        if (i > 0)
            k_deform<<<dim3(1024, i), 256, 0, stream>>>(RDcur, def, RDnxt);

        // ---- v path ----
        for (int b0 = 0; b0 < BB; b0 += HB){
            k_conv1<<<dim3(32, 32, HB), 256, 0, stream>>>(
                def, 2 * HW, def + HW, 2 * HW, img_i, HW, vw1 + (size_t)i * 2700, h1, b0);
            k_conv2<<<dim3(8, 32, HB), 256, 0, stream>>>(
                h1, wp + (size_t)(NL + i) * 129024, h2);
            k_conv3<2><<<dim3(8, 32, HB), 256, 0, stream>>>(
                h2, wr3 + 5760 + (size_t)i * 2304, nullptr, vtmp, nullptr, b0);
        }
        k_blur_h<<<2048, 256, 0, stream>>>(vtmp, btmp);
        k_blur_v<<<dim3(4, 8, 8), 256, 0, stream>>>(
            btmp, fields + (size_t)i * BB * 2 * HW, def);

        // ---- finalize ----
        k_final<<<1024, 256, 0, stream>>>(def, source, seg, RDnxt, i + 1, img_ip);
        k_grad<<<1024, 256, 0, stream>>>(img_ip, grads + (size_t)(i + 1) * BB * 2 * HW);

        float* t = RDcur; RDcur = RDnxt; RDnxt = t;
    }
}

// Round 4
// 2068.973 us; speedup vs baseline: 5.2723x; 5.2723x over previous
//
#include <hip/hip_runtime.h>
#include <math.h>

#define HW 65536
#define BB 4
#define NL 5

typedef short s8v __attribute__((ext_vector_type(8)));
typedef float f4v __attribute__((ext_vector_type(4)));
typedef unsigned short u16;

#define AS1 __attribute__((address_space(1)))
#define AS3 __attribute__((address_space(3)))

__device__ __forceinline__ float leaky_f(float x){ return x >= 0.f ? x : 0.01f * x; }

__device__ __forceinline__ u16 f2bf(float x){
    union { float f; unsigned u; } v; v.f = x;
    unsigned r = v.u + 0x7FFF + ((v.u >> 16) & 1);
    return (u16)(r >> 16);
}
__device__ __forceinline__ float bf2f(u16 h){
    union { unsigned u; float f; } v; v.u = ((unsigned)h) << 16;
    return v.f;
}

// ---------------------------------------------------------------------------
// init / gradient
// ---------------------------------------------------------------------------
__global__ void k_init(const float* __restrict__ src, const float* __restrict__ z0,
                       float* __restrict__ images0, float* __restrict__ resid0,
                       float* __restrict__ def){
    int p = blockIdx.x * 256 + threadIdx.x;
    int b = p >> 16, q = p & 65535;
    images0[p] = src[p];
    resid0[p]  = z0[q];
    int x = q & 255, y = q >> 8;
    def[(size_t)(b * 2 + 0) * HW + q] = (float)x;
    def[(size_t)(b * 2 + 1) * HW + q] = (float)y;
}

__global__ void k_grad(const float* __restrict__ img, float* __restrict__ gout){
    int p = blockIdx.x * 256 + threadIdx.x;
    int b = p >> 16, q = p & 65535;
    int x = q & 255, y = q >> 8;
    const float* ib = img + (size_t)b * HW;
    int xm = max(x - 1, 0), xp = min(x + 1, 255);
    int ym = max(y - 1, 0), yp = min(y + 1, 255);
    float a00 = ib[ym * 256 + xm], a01 = ib[ym * 256 + x], a02 = ib[ym * 256 + xp];
    float a10 = ib[y  * 256 + xm],                         a12 = ib[y  * 256 + xp];
    float a20 = ib[yp * 256 + xm], a21 = ib[yp * 256 + x], a22 = ib[yp * 256 + xp];
    float gx = (a02 - a00 + 2.f * (a12 - a10) + a22 - a20) * 0.125f;
    float gy = (a20 - a00 + 2.f * (a21 - a01) + a22 - a02) * 0.125f;
    gout[(size_t)(b * 2 + 0) * HW + q] = gx;
    gout[(size_t)(b * 2 + 1) * HW + q] = gy;
}

// conv2 weights -> MFMA fragment order (lane&15 = oc-within-tile, quad*8+j = ic)
__global__ void k_packw(const float* __restrict__ zw2, const float* __restrict__ vw2,
                        u16* __restrict__ wp){
    int idx = blockIdx.x * 256 + threadIdx.x;     // < 1,290,240
    int lane9 = idx & 511, chunk = idx >> 9;
    int nt = chunk % 7; int t = chunk / 7;
    int ks = t % 4; t >>= 2;
    int off = t % 9; t /= 9;
    int layer = t % 5, path = t / 5;
    int lane = lane9 >> 3, j = lane9 & 7;
    int ic = ks * 32 + (lane >> 4) * 8 + j;
    int oc = nt * 16 + (lane & 15);
    const float* w = path ? vw2 : zw2;
    float v = 0.f;
    if (ic < 100 && oc < 100)
        v = w[(((size_t)layer * 100 + oc) * 100 + ic) * 9 + off];
    wp[idx] = f2bf(v);
}

// conv3 weights -> B-fragment order: slot = path*5+layer; chunk = (off*4+ks);
// within chunk: lane*8+j, lane&15 = oc (only oc<N nonzero), (lane>>4)*8+j = ic
__global__ void k_packw3(const float* __restrict__ zw3, const float* __restrict__ vw3,
                         u16* __restrict__ wq){
    int idx = blockIdx.x * 256 + threadIdx.x;     // < 184,320
    if (idx >= 184320) return;
    int lane9 = idx & 511, chunk = idx >> 9;
    int ks = chunk & 3; int t = chunk >> 2;
    int off = t % 9; int slot = t / 9;
    int lane = lane9 >> 3, j = lane9 & 7;
    int ic = ks * 32 + (lane >> 4) * 8 + j;
    int oc = lane & 15;
    float v = 0.f;
    if (ic < 100){
        if (slot < 5){ if (oc == 0) v = zw3[((size_t)slot * 100 + ic) * 9 + off]; }
        else { int layer = slot - 5;
               if (oc < 2) v = vw3[(((size_t)layer * 2 + oc) * 100 + ic) * 9 + off]; }
    }
    wq[idx] = f2bf(v);
}

// ---------------------------------------------------------------------------
// conv1: 3 fp32 planes -> h1 NHWC bf16[128] (leaky; oc>=100 zero)  [R2 verbatim]
// ---------------------------------------------------------------------------
__global__ __launch_bounds__(256)
void k_conv1(const float* __restrict__ p0, int s0, const float* __restrict__ p1, int s1,
             const float* __restrict__ p2, int s2, const float* __restrict__ w1,
             u16* __restrict__ h1, int b0){
    __shared__ float t3[300];
    __shared__ float wl[2700];
    const int tid = threadIdx.x;
    const int tX = blockIdx.x, tY = blockIdx.y, bz = blockIdx.z;
    const int b = b0 + bz;
    const int y0 = tY * 8 - 1, x0 = tX * 8 - 1;
    for (int idx = tid; idx < 300; idx += 256){
        int ch = idx / 100, p = idx - ch * 100;
        int r = p / 10, c = p - r * 10;
        int gy = y0 + r, gx = x0 + c;
        const float* pp = (ch == 0) ? p0 + (size_t)b * s0
                        : (ch == 1) ? p1 + (size_t)b * s1 : p2 + (size_t)b * s2;
        t3[idx] = ((unsigned)gy < 256u && (unsigned)gx < 256u) ? pp[gy * 256 + gx] : 0.f;
    }
    for (int idx = tid; idx < 2700; idx += 256) wl[idx] = w1[idx];
    __syncthreads();

    const int px = tid & 63, g = tid >> 6;
    const int row = px >> 3, colx = px & 7;
    float iv[27];
    #pragma unroll
    for (int c3 = 0; c3 < 3; c3++)
        #pragma unroll
        for (int dr = 0; dr < 3; dr++)
            #pragma unroll
            for (int dc = 0; dc < 3; dc++)
                iv[c3 * 9 + dr * 3 + dc] = t3[c3 * 100 + (row + dr) * 10 + colx + dc];

    const int gy = tY * 8 + row, gx = tX * 8 + colx;
    u16* dst = h1 + (((size_t)bz * HW + (size_t)(gy * 256 + gx)) << 7) + g * 32;
    #pragma unroll
    for (int s = 0; s < 4; s++){
        int ov[4];
        #pragma unroll
        for (int hp = 0; hp < 4; hp++){
            u16 lo = 0, hi = 0;
            #pragma unroll
            for (int e = 0; e < 2; e++){
                int oc = g * 32 + s * 8 + hp * 2 + e;
                u16 hv = 0;
                if (oc < 100){
                    const float* wk = &wl[oc * 27];
                    float a = 0.f;
                    #pragma unroll
                    for (int q = 0; q < 27; q++) a = fmaf(wk[q], iv[q], a);
                    hv = f2bf(leaky_f(a));
                }
                if (e) hi = hv; else lo = hv;
            }
            ov[hp] = (int)lo | ((int)hi << 16);
        }
        *(int4*)(dst + s * 8) = make_int4(ov[0], ov[1], ov[2], ov[3]);
    }
}

// ---------------------------------------------------------------------------
// async DMA staging of a 34x10 halo tile, one 32-ic slab per ks.
// LDS layout: slot idx=px*4+part at idx*16B; slot holds global ic-chunk
// part ^ ((px>>1)&3)  (XOR swizzle, 0 bank conflicts measured in R3).
// OOB lanes read a guaranteed-zero 16B block (pad channels 112..119) w/ step 0.
// ---------------------------------------------------------------------------
__device__ __forceinline__ void dma_setup(const u16* __restrict__ h, size_t hbase,
                                          int y0, int x0, int tid,
                                          const u16** gp, int* gstep){
    const u16* zpad = h + (hbase << 7) + 112;     // channels 112..119 == 0
    #pragma unroll
    for (int s = 0; s < 6; s++){
        int idx = tid + s * 256;
        const u16* g = zpad; int st = 0;
        if (idx < 1360){
            int px = idx >> 2, part = idx & 3;
            int hr = px / 34, hc = px - hr * 34;
            int gy = y0 + hr, gx = x0 + hc;
            if ((unsigned)gy < 256u && (unsigned)gx < 256u){
                g = h + ((hbase + (size_t)(gy * 256 + gx)) << 7) + (part ^ ((px >> 1) & 3)) * 8;
                st = 32;
            }
        }
        gp[s] = g; gstep[s] = st;
    }
}

__device__ __forceinline__ void dma_slab(const u16** gp, const int* gstep,
                                         short* Lnxt, int wv){
    #pragma unroll
    for (int s = 0; s < 6; s++){
        __builtin_amdgcn_global_load_lds(
            (const AS1 unsigned int*)(unsigned long long)(const void*)gp[s],
            (AS3 unsigned int*)(unsigned long long)(void*)(&Lnxt[(s * 256 + wv * 64) * 8]),
            16, 0, 0);
        gp[s] += gstep[s];
    }
}

// ---------------------------------------------------------------------------
// conv2: 100->100 3x3 implicit GEMM, A=weights (M=oc), B=acts (N=px).
// block 256 = 4 waves, out tile 32x8 px. DMA double-buffer, 1 barrier/ks.
// D: row=quad*4+reg=oc, col=lane&15=px -> 8B bf16 stores.
// ---------------------------------------------------------------------------
__global__ __launch_bounds__(256, 2)
void k_conv2(const u16* __restrict__ h1, const u16* __restrict__ wp, u16* __restrict__ h2){
    __shared__ __align__(16) short lds[2][12288];
    const int tid = threadIdx.x;
    const int lane = tid & 63, wv = tid >> 6;
    const int quad = lane >> 4, m = lane & 15;
    const int tX = blockIdx.x, tY = blockIdx.y, bz = blockIdx.z;
    const int y0 = tY * 8 - 1, x0 = tX * 32 - 1;
    const size_t hbase = (size_t)bz << 16;

    f4v acc[4][7];
    #pragma unroll
    for (int t = 0; t < 4; t++)
        #pragma unroll
        for (int n = 0; n < 7; n++){
            acc[t][n][0] = 0.f; acc[t][n][1] = 0.f; acc[t][n][2] = 0.f; acc[t][n][3] = 0.f;
        }

    const u16* gp[6]; int gstep[6];
    dma_setup(h1, hbase, y0, x0, tid, gp, gstep);
    dma_slab(gp, gstep, lds[0], wv);              // ks=0 -> buf0

    for (int ks = 0; ks < 4; ks++){
        __syncthreads();                          // drains vmcnt -> buf[ks&1] ready
        const short* L = lds[ks & 1];
        short* Lnxt = lds[(ks + 1) & 1];
        const bool pre = (ks < 3);
        #pragma unroll
        for (int off = 0; off < 9; off++){
            if (off == 4 && pre) dma_slab(gp, gstep, Lnxt, wv);  // overlap w/ MFMA
            const int dr = off / 3, dc = off - dr * 3;
            s8v bf[4];
            #pragma unroll
            for (int t = 0; t < 4; t++){
                int hpx = (2 * wv + (t >> 1) + dr) * 34 + (t & 1) * 16 + dc + m;
                bf[t] = *(const s8v*)&L[hpx * 32 + ((quad ^ ((hpx >> 1) & 3)) << 3)];
            }
            const u16* wb = wp + (size_t)((off * 4 + ks) * 7) * 512 + lane * 8;
            #pragma unroll
            for (int nt = 0; nt < 7; nt++){
                s8v af = *(const s8v*)(wb + nt * 512);
                #pragma unroll
                for (int t = 0; t < 4; t++)
                    acc[t][nt] = __builtin_amdgcn_mfma_f32_16x16x32_bf16(af, bf[t], acc[t][nt], 0, 0, 0);
            }
        }
    }

    // epilogue: oc = nt*16 + quad*4 + reg at px col m (verified in R3)
    #pragma unroll
    for (int t = 0; t < 4; t++){
        int gy = tY * 8 + 2 * wv + (t >> 1);
        int gx = tX * 32 + (t & 1) * 16 + m;
        u16* base = h2 + ((hbase + (size_t)(gy * 256 + gx)) << 7);
        #pragma unroll
        for (int nt = 0; nt < 7; nt++){
            unsigned lo = (unsigned)f2bf(leaky_f(acc[t][nt][0])) |
                          ((unsigned)f2bf(leaky_f(acc[t][nt][1])) << 16);
            unsigned hi = (unsigned)f2bf(leaky_f(acc[t][nt][2])) |
                          ((unsigned)f2bf(leaky_f(acc[t][nt][3])) << 16);
            *(int2*)(base + nt * 16 + quad * 4) = make_int2((int)lo, (int)hi);
        }
    }
    { // zero pad channels 112..127 (keeps zpad + conv3 staging clean)
        int gy = tY * 8 + (tid >> 5), gx = tX * 32 + (tid & 31);
        u16* p = h2 + ((hbase + (size_t)(gy * 256 + gx)) << 7);
        *(int4*)(p + 112) = make_int4(0, 0, 0, 0);
        *(int4*)(p + 120) = make_int4(0, 0, 0, 0);
    }
}

// ---------------------------------------------------------------------------
// conv3: 100->N implicit GEMM via MFMA, A=acts (M=px), B=weights (N=oc<N).
// Same staging as conv2. D: row=quad*4+reg=px, col=lane&15=oc.
// ---------------------------------------------------------------------------
template<int N>
__global__ __launch_bounds__(256, 2)
void k_conv3(const u16* __restrict__ h2, const u16* __restrict__ wq,
             const float* __restrict__ rprev, float* __restrict__ out0,
             float* __restrict__ out1, int b0){
    __shared__ __align__(16) short lds[2][12288];
    const int tid = threadIdx.x;
    const int lane = tid & 63, wv = tid >> 6;
    const int quad = lane >> 4, m = lane & 15;
    const int tX = blockIdx.x, tY = blockIdx.y, bz = blockIdx.z;
    const int y0 = tY * 8 - 1, x0 = tX * 32 - 1;
    const size_t hbase = (size_t)bz << 16;

    f4v acc[4];
    #pragma unroll
    for (int t = 0; t < 4; t++){ acc[t][0]=0.f; acc[t][1]=0.f; acc[t][2]=0.f; acc[t][3]=0.f; }

    const u16* gp[6]; int gstep[6];
    dma_setup(h2, hbase, y0, x0, tid, gp, gstep);
    dma_slab(gp, gstep, lds[0], wv);

    for (int ks = 0; ks < 4; ks++){
        __syncthreads();
        const short* L = lds[ks & 1];
        short* Lnxt = lds[(ks + 1) & 1];
        const bool pre = (ks < 3);
        #pragma unroll
        for (int off = 0; off < 9; off++){
            if (off == 4 && pre) dma_slab(gp, gstep, Lnxt, wv);
            const int dr = off / 3, dc = off - dr * 3;
            s8v wf = *(const s8v*)(wq + (size_t)((off * 4 + ks)) * 512 + lane * 8);
            #pragma unroll
            for (int t = 0; t < 4; t++){
                int hpx = (2 * wv + (t >> 1) + dr) * 34 + (t & 1) * 16 + dc + m;
                s8v af = *(const s8v*)&L[hpx * 32 + ((quad ^ ((hpx >> 1) & 3)) << 3)];
                acc[t] = __builtin_amdgcn_mfma_f32_16x16x32_bf16(af, wf, acc[t], 0, 0, 0);
            }
        }
    }

    const int b = b0 + bz;
    #pragma unroll
    for (int t = 0; t < 4; t++){
        int gy = tY * 8 + 2 * wv + (t >> 1);
        int gx = tX * 32 + (t & 1) * 16 + quad * 4;
        size_t p = (size_t)gy * 256 + gx;
        if (N == 1){
            if (m == 0){
                float4 rp = *(const float4*)&rprev[(size_t)b * HW + p];
                float4 v = make_float4(rp.x + acc[t][0] * 0.2f, rp.y + acc[t][1] * 0.2f,
                                       rp.z + acc[t][2] * 0.2f, rp.w + acc[t][3] * 0.2f);
                *(float4*)&out0[(size_t)b * HW + p] = v;
                *(float4*)&out1[(size_t)b * HW + p] = v;
            }
        } else {
            if (m < 2){
                float4 v = make_float4(acc[t][0], acc[t][1], acc[t][2], acc[t][3]);
                *(float4*)&out0[((size_t)(b * 2) + m) * HW + p] = v;
            }
        }
    }
}

// ---------------------------------------------------------------------------
// bilinear warp + blurs + final (R2 verbatim)
// ---------------------------------------------------------------------------
__device__ __forceinline__ float bilin(const float* __restrict__ img, float x, float y){
    float x0 = floorf(x), y0 = floorf(y);
    float wx = x - x0, wy = y - y0;
    float r = 0.f;
    #pragma unroll
    for (int dy = 0; dy < 2; dy++){
        float yi = y0 + (float)dy;
        if (yi < 0.f || yi > 255.f) continue;
        int iy = (int)yi;
        float wyv = dy ? wy : 1.f - wy;
        #pragma unroll
        for (int dx = 0; dx < 2; dx++){
            float xi = x0 + (float)dx;
            if (xi < 0.f || xi > 255.f) continue;
            int ix = (int)xi;
            float wxv = dx ? wx : 1.f - wx;
            r += wyv * wxv * img[iy * 256 + ix];
        }
    }
    return r;
}

__global__ void k_deform(const float* __restrict__ rdin, const float* __restrict__ def,
                         float* __restrict__ rdout){
    int p = blockIdx.x * 256 + threadIdx.x;
    int j = blockIdx.y;
    int b = p >> 16, q = p & 65535;
    float x = def[(size_t)(b * 2 + 0) * HW + q];
    float y = def[(size_t)(b * 2 + 1) * HW + q];
    rdout[(size_t)j * BB * HW + p] = bilin(rdin + (size_t)j * BB * HW + (size_t)b * HW, x, y);
}

__global__ void k_blur_h(const float* __restrict__ in, float* __restrict__ outb){
    __shared__ float g[51];
    __shared__ float row[306];
    __shared__ float ginv;
    int tid = threadIdx.x;
    int rid = blockIdx.x;
    int ch = rid >> 8, y = rid & 255;
    if (tid < 51){ float d = (float)tid - 25.f; g[tid] = expf(-0.005f * d * d); }
    row[tid + 25] = in[(size_t)ch * HW + y * 256 + tid];
    if (tid < 25) row[tid] = 0.f;
    if (tid >= 231) row[tid + 50] = 0.f;
    __syncthreads();
    if (tid == 0){ float s = 0.f; for (int k = 0; k < 51; k++) s += g[k]; ginv = 1.f / s; }
    __syncthreads();
    float acc = 0.f;
    for (int k = 0; k < 51; k++) acc = fmaf(g[k], row[tid + k], acc);
    outb[(size_t)ch * HW + y * 256 + tid] = acc * ginv;
}

__global__ void k_blur_v(const float* __restrict__ in, float* __restrict__ fout,
                         float* __restrict__ def){
    __shared__ float g[51];
    __shared__ float ginv;
    __shared__ float tb[82 * 64];
    int tid = threadIdx.x;
    int tX = blockIdx.x, tY = blockIdx.y, ch = blockIdx.z;
    if (tid < 51){ float d = (float)tid - 25.f; g[tid] = expf(-0.005f * d * d); }
    for (int idx = tid; idx < 82 * 64; idx += 256){
        int r = idx >> 6, c = idx & 63;
        int gy = tY * 32 + r - 25, gx = tX * 64 + c;
        tb[idx] = (gy >= 0 && gy < 256) ? in[(size_t)ch * HW + gy * 256 + gx] : 0.f;
    }
    __syncthreads();
    if (tid == 0){ float s = 0.f; for (int k = 0; k < 51; k++) s += g[k]; ginv = 1.f / s; }
    __syncthreads();
    int c = tid & 63, r0 = (tid >> 6) * 8;
    for (int k = 0; k < 8; k++){
        int r = r0 + k;
        float acc = 0.f;
        for (int t = 0; t < 51; t++) acc = fmaf(g[t], tb[(r + t) * 64 + c], acc);
        acc *= ginv;
        int y = tY * 32 + r, x = tX * 64 + c;
        fout[(size_t)ch * HW + y * 256 + x] = acc;
        def [(size_t)ch * HW + y * 256 + x] -= acc * 0.2f;
    }
}

__global__ void k_final(const float* __restrict__ def, const float* __restrict__ src,
                        const float* __restrict__ seg, const float* __restrict__ rdbase,
                        int nrd, float* __restrict__ imgout){
    int p = blockIdx.x * 256 + threadIdx.x;
    int b = p >> 16, q = p & 65535;
    float x = def[(size_t)(b * 2 + 0) * HW + q];
    float y = def[(size_t)(b * 2 + 1) * HW + q];
    float mk = bilin(seg + (size_t)b * HW, x, y);
    float s = bilin(src + (size_t)b * HW, x, y);
    float acc = 0.f;
    for (int j = 0; j < nrd; j++) acc += rdbase[(size_t)j * BB * HW + p];
    imgout[p] = s + acc * 8e-5f * mk;
}

// ---------------------------------------------------------------------------
extern "C" void kernel_launch(void* const* d_in, const int* in_sizes, int n_in,
                              void* d_out, int out_size, void* d_ws, size_t ws_size,
                              hipStream_t stream){
    const float* source = (const float*)d_in[0];
    const float* seg    = (const float*)d_in[1];
    const float* z0     = (const float*)d_in[2];
    const float* zw1    = (const float*)d_in[3];
    const float* zw2    = (const float*)d_in[4];
    const float* zw3    = (const float*)d_in[5];
    const float* vw1    = (const float*)d_in[6];
    const float* vw2    = (const float*)d_in[7];
    const float* vw3    = (const float*)d_in[8];

    float* out = (float*)d_out;
    float* images = out;                       // (6,B,1,HW)
    float* fields = out + 1572864;             // (5,B,2,HW)
    float* resid  = out + 4194304;             // (6,B,1,HW)
    float* grads  = out + 5767168;             // (6,B,2,HW)

    float* ws = (float*)d_ws;
    float* def  = ws;                          // 524288
    float* RDa  = def  + 524288;               // 1310720
    float* RDb  = RDa  + 1310720;              // 1310720
    float* vtmp = RDb  + 1310720;              // 524288
    float* btmp = vtmp + 524288;               // 524288
    u16*   wp   = (u16*)(btmp + 524288);       // 1,290,240 u16
    u16*   wq3  = wp + 1290240;                // 184,320 u16
    u16*   h1   = wq3 + 184320;

    size_t need4 = 4194304ull * 4 + 1290240ull * 2 + 184320ull * 2 + 2ull * 4 * 16777216ull;
    const int HB = (ws_size >= need4) ? 4 : 1;
    u16* h2 = h1 + (size_t)HB * 8388608;       // HB*HW*128

    k_packw <<<5040, 256, 0, stream>>>(zw2, vw2, wp);
    k_packw3<<<720, 256, 0, stream>>>(zw3, vw3, wq3);
    k_init  <<<1024, 256, 0, stream>>>(source, z0, images, resid, def);
    k_grad  <<<1024, 256, 0, stream>>>(source, grads);

    float* RDcur = RDa;
    float* RDnxt = RDb;

    for (int i = 0; i < NL; i++){
        float* res_i  = resid  + (size_t)i * BB * HW;
        float* res_ip = resid  + (size_t)(i + 1) * BB * HW;
        float* img_i  = images + (size_t)i * BB * HW;
        float* img_ip = images + (size_t)(i + 1) * BB * HW;

        // ---- z path ----
        for (int b0 = 0; b0 < BB; b0 += HB){
            k_conv1<<<dim3(32, 32, HB), 256, 0, stream>>>(
                res_i, HW, img_i, HW, images, HW, zw1 + (size_t)i * 2700, h1, b0);
            k_conv2<<<dim3(8, 32, HB), 256, 0, stream>>>(
                h1, wp + (size_t)i * 129024, h2);
            k_conv3<1><<<dim3(8, 32, HB), 256, 0, stream>>>(
                h2, wq3 + (size_t)i * 18432, res_i, res_ip,
                RDnxt + (size_t)i * BB * HW, b0);
        }

        // ---- deform previously-deformed residuals (pre-update def) ----
        if (i > 0)
            k_deform<<<dim3(1024, i), 256, 0, stream>>>(RDcur, def, RDnxt);

        // ---- v path ----
        for (int b0 = 0; b0 < BB; b0 += HB){
            k_conv1<<<dim3(32, 32, HB), 256, 0, stream>>>(
                def, 2 * HW, def + HW, 2 * HW, img_i, HW, vw1 + (size_t)i * 2700, h1, b0);
            k_conv2<<<dim3(8, 32, HB), 256, 0, stream>>>(
                h1, wp + (size_t)(NL + i) * 129024, h2);
            k_conv3<2><<<dim3(8, 32, HB), 256, 0, stream>>>(
                h2, wq3 + (size_t)(NL + i) * 18432, nullptr, vtmp, nullptr, b0);
        }
        k_blur_h<<<2048, 256, 0, stream>>>(vtmp, btmp);
        k_blur_v<<<dim3(4, 8, 8), 256, 0, stream>>>(
            btmp, fields + (size_t)i * BB * 2 * HW, def);

        // ---- finalize ----
        k_final<<<1024, 256, 0, stream>>>(def, source, seg, RDnxt, i + 1, img_ip);
        k_grad<<<1024, 256, 0, stream>>>(img_ip, grads + (size_t)(i + 1) * BB * 2 * HW);

        float* t = RDcur; RDcur = RDnxt; RDnxt = t;
    }
}